// Round 5
// baseline (5601.490 us; speedup 1.0000x reference)
//
#include <hip/hip_runtime.h>

// ============================================================================
// SequentialVariationalIB: 2-layer LSTM (B=8,S=512,H=512) + VIB head + decoder
//
//  Sequential core: 64 L0-blocks + 128 L1-blocks, decoupled chains.
//  Cross-block h exchange via SINGLE 8-byte atomic words {f32 h | u32 stamp}:
//  the data IS the flag (no fences, no vmcnt, no separate signal store).
//  Consumers poll their own staging slice; on detect the h values are already
//  in registers.
// ============================================================================

typedef __attribute__((ext_vector_type(4))) float f32x4;
typedef __attribute__((ext_vector_type(8))) short short8;
typedef __attribute__((ext_vector_type(4))) unsigned short u16x4;

#define V_SZ 32000
#define E_SZ 512
#define H_SZ 512
#define B_SZ 8
#define S_SZ 512
#define NTOK 4096            // B*S
#define G4H  2048            // 4*H

// ---------------------------------------------------------------------------
// bf16 helpers (manual RNE)
// ---------------------------------------------------------------------------
__device__ __forceinline__ unsigned short f2bf(float x) {
  unsigned int b = __float_as_uint(x);
  b += 0x7FFFu + ((b >> 16) & 1u);
  return (unsigned short)(b >> 16);
}
__device__ __forceinline__ float bf2f(unsigned short u) {
  return __uint_as_float(((unsigned int)u) << 16);
}

__device__ __forceinline__ void split4(const f32x4 v, u16x4& hv, u16x4& lv) {
  unsigned short h0 = f2bf(v.x); lv.x = f2bf(v.x - bf2f(h0)); hv.x = h0;
  unsigned short h1 = f2bf(v.y); lv.y = f2bf(v.y - bf2f(h1)); hv.y = h1;
  unsigned short h2 = f2bf(v.z); lv.z = f2bf(v.z - bf2f(h2)); hv.z = h2;
  unsigned short h3 = f2bf(v.w); lv.w = f2bf(v.w - bf2f(h3)); hv.w = h3;
}

// ---------------------------------------------------------------------------
// prep kernels
// ---------------------------------------------------------------------------
__global__ void split_kernel(const float* __restrict__ src,
                             unsigned short* __restrict__ hi,
                             unsigned short* __restrict__ lo, int n4) {
  int i = blockIdx.x * 256 + threadIdx.x;
  if (i >= n4) return;
  f32x4 v = ((const f32x4*)src)[i];
  u16x4 hv, lv;
  split4(v, hv, lv);
  ((u16x4*)hi)[i] = hv;
  ((u16x4*)lo)[i] = lv;
}

__global__ void bias_sum_kernel(const float* __restrict__ a0, const float* __restrict__ c0,
                                const float* __restrict__ a1, const float* __restrict__ c1,
                                float* __restrict__ o0, float* __restrict__ o1) {
  int i = blockIdx.x * 256 + threadIdx.x;
  if (i < G4H) { o0[i] = a0[i] + c0[i]; o1[i] = a1[i] + c1[i]; }
}

__global__ void embed_split_kernel(const float* __restrict__ emb, const int* __restrict__ x,
                                   unsigned short* __restrict__ hi, unsigned short* __restrict__ lo) {
  int gid = blockIdx.x * 256 + threadIdx.x;   // NTOK * 128
  int r = gid >> 7;
  int kq = (gid & 127) << 2;
  int tok = x[r];
  f32x4 v = *(const f32x4*)(emb + (size_t)tok * E_SZ + kq);
  u16x4 hv, lv;
  split4(v, hv, lv);
  *(u16x4*)(hi + (size_t)r * E_SZ + kq) = hv;
  *(u16x4*)(lo + (size_t)r * E_SZ + kq) = lv;
}

// ---------------------------------------------------------------------------
// split-bf16 3-product GEMM:  C[M,N] = A[M,K] @ B[N,K]^T + bias
// ---------------------------------------------------------------------------
__device__ __forceinline__ int swz32(int row, int seg) {
  return row * 32 + (((seg ^ (row & 3)) << 3));
}

__global__ __launch_bounds__(256, 2) void gemm3_kernel(
    const unsigned short* __restrict__ Ah, const unsigned short* __restrict__ Al,
    const unsigned short* __restrict__ Bh, const unsigned short* __restrict__ Bl,
    const float* __restrict__ bias, float* __restrict__ C,
    int M, int N, int K) {
  __shared__ unsigned short sAh[128 * 32];
  __shared__ unsigned short sAl[128 * 32];
  __shared__ unsigned short sBh[128 * 32];
  __shared__ unsigned short sBl[128 * 32];

  const int t = threadIdx.x;
  const int lane = t & 63;
  const int wave = t >> 6;
  const int wr = wave >> 1, wc = wave & 1;
  const size_t m0 = (size_t)blockIdx.y * 128;
  const size_t n0 = (size_t)blockIdx.x * 128;

  f32x4 acc[4][4];
#pragma unroll
  for (int i = 0; i < 4; ++i)
#pragma unroll
    for (int j = 0; j < 4; ++j) acc[i][j] = (f32x4){0.f, 0.f, 0.f, 0.f};

  const int r0 = t >> 2;
  const int seg0 = t & 3;

  const int nk = K >> 5;
  for (int ks = 0; ks < nk; ++ks) {
    const int k0 = ks << 5;
    short8 vAh[2], vAl[2], vBh[2], vBl[2];
#pragma unroll
    for (int r = 0; r < 2; ++r) {
      int row = r0 + r * 64;
      size_t ga = (m0 + row) * (size_t)K + k0 + seg0 * 8;
      size_t gb = (n0 + row) * (size_t)K + k0 + seg0 * 8;
      vAh[r] = *(const short8*)(Ah + ga);
      vAl[r] = *(const short8*)(Al + ga);
      vBh[r] = *(const short8*)(Bh + gb);
      vBl[r] = *(const short8*)(Bl + gb);
    }
    __syncthreads();
#pragma unroll
    for (int r = 0; r < 2; ++r) {
      int row = r0 + r * 64;
      int d = swz32(row, seg0);
      *(short8*)(sAh + d) = vAh[r];
      *(short8*)(sAl + d) = vAl[r];
      *(short8*)(sBh + d) = vBh[r];
      *(short8*)(sBl + d) = vBl[r];
    }
    __syncthreads();

    short8 ah[4], al[4], bh[4], bl[4];
    const int seg = lane >> 4;
#pragma unroll
    for (int m = 0; m < 4; ++m) {
      int row = wr * 64 + m * 16 + (lane & 15);
      int d = swz32(row, seg);
      ah[m] = *(const short8*)(sAh + d);
      al[m] = *(const short8*)(sAl + d);
    }
#pragma unroll
    for (int n = 0; n < 4; ++n) {
      int row = wc * 64 + n * 16 + (lane & 15);
      int d = swz32(row, seg);
      bh[n] = *(const short8*)(sBh + d);
      bl[n] = *(const short8*)(sBl + d);
    }
#pragma unroll
    for (int m = 0; m < 4; ++m) {
#pragma unroll
      for (int n = 0; n < 4; ++n) {
        acc[m][n] = __builtin_amdgcn_mfma_f32_16x16x32_bf16(ah[m], bh[n], acc[m][n], 0, 0, 0);
        acc[m][n] = __builtin_amdgcn_mfma_f32_16x16x32_bf16(ah[m], bl[n], acc[m][n], 0, 0, 0);
        acc[m][n] = __builtin_amdgcn_mfma_f32_16x16x32_bf16(al[m], bh[n], acc[m][n], 0, 0, 0);
      }
    }
  }

#pragma unroll
  for (int m = 0; m < 4; ++m) {
#pragma unroll
    for (int n = 0; n < 4; ++n) {
      size_t gr0 = m0 + wr * 64 + m * 16 + ((lane >> 4) << 2);
      size_t gc = n0 + wc * 64 + n * 16 + (lane & 15);
      float bv = bias ? bias[gc] : 0.f;
#pragma unroll
      for (int j = 0; j < 4; ++j) {
        C[(gr0 + j) * (size_t)N + gc] = acc[m][n][j] + bv;
      }
    }
  }
}

// ---------------------------------------------------------------------------
// persistent sequential LSTM kernel — data-as-flag signaling
// h0s/h1s: [512 steps][4096 words]; word = {u32 stamp | f32 h} at
// index b*512 + unit. Producer cell lane stores one packed word; consumers
// poll their staging slice directly (re-loading only pending words).
// ---------------------------------------------------------------------------
#define SEQ_NB 192
#define SEQ_NB_L0 64

__device__ __forceinline__ float sigm(float x) { return 1.f / (1.f + expf(-x)); }

__device__ __forceinline__ unsigned long long ldw(const unsigned long long* p) {
  return __hip_atomic_load(p, __ATOMIC_RELAXED, __HIP_MEMORY_SCOPE_AGENT);
}

__global__ __launch_bounds__(256) void lstm_seq_kernel(
    const float* __restrict__ gx0,    // [4096][2048] (bias folded in)
    const float* __restrict__ w_hh0,  // [2048][512]
    const float* __restrict__ w_ih1,  // [2048][512]
    const float* __restrict__ w_hh1,  // [2048][512]
    const float* __restrict__ b1s,    // [2048]
    const float* __restrict__ initst, // [2][2][512]
    unsigned long long* __restrict__ h0s,  // [512][4096]
    unsigned long long* __restrict__ h1s,  // [512][4096]
    unsigned short* __restrict__ hs1h,// [4096][512]
    unsigned short* __restrict__ hs1l) {
  const int blk = blockIdx.x;
  const int t = threadIdx.x;
  const bool isL1 = (blk >= SEQ_NB_L0);
  const int lb = isL1 ? (blk - SEQ_NB_L0) : blk;
  const int rg = t >> 4;
  const int kg = t & 15;

  __shared__ float hA[8][512];
  __shared__ float hB[8][512];
  __shared__ float gates_s[32][8];

  // staging slice: 16 consecutive words per thread
  const int wbase = t * 16;          // in [0, 4096)
  const int sb = wbase >> 9;         // batch
  const int sk = wbase & 511;        // k start

  // ---- weights -> registers (interleaved k-slices) ----
  f32x4 w[16];
  if (!isL1) {
#pragma unroll
    for (int rr = 0; rr < 2; ++rr) {
      int rl = rg * 2 + rr;
      int grow = (rl >> 3) * H_SZ + lb * 8 + (rl & 7);
      const float* src = w_hh0 + (size_t)grow * H_SZ + kg * 4;
#pragma unroll
      for (int j = 0; j < 8; ++j) w[rr * 8 + j] = *(const f32x4*)(src + j * 64);
    }
  } else {
    int grow = (rg >> 2) * H_SZ + lb * 4 + (rg & 3);
    const float* src = ((kg < 8) ? w_ih1 : w_hh1) + (size_t)grow * H_SZ + (kg & 7) * 4;
#pragma unroll
    for (int j = 0; j < 16; ++j) w[j] = *(const f32x4*)(src + j * 32);
  }

  // ---- per-lane cell state (wave 0 only) ----
  const int UPB = isL1 ? 4 : 8;
  const int nCell = UPB * 8;                       // 64 (L0) / 32 (L1)
  const int cu = t >> 3, cb = t & 7;
  const int cunit = lb * UPB + cu;
  float creg = 0.f;
  float bgi = 0.f, bgf = 0.f, bgg = 0.f, bgo = 0.f;
  if (t < nCell) {
    creg = initst[1024 + (isL1 ? 512 : 0) + cunit];
    if (isL1) {
      bgi = b1s[cunit];
      bgf = b1s[512 + cunit];
      bgg = b1s[1024 + cunit];
      bgo = b1s[1536 + cunit];
    }
  }

  for (int step = 0; step < 512; ++step) {
    // ---- prefetch gx0 gate rows for this step (cacheable) ----
    float pgi = 0.f, pgf = 0.f, pgg = 0.f, pgo = 0.f;
    if (!isL1 && t < nCell) {
      const float* gx = gx0 + ((size_t)(cb * S_SZ + step)) * G4H + cunit;
      pgi = gx[0];
      pgf = gx[512];
      pgg = gx[1024];
      pgo = gx[1536];
    }

    // ---- poll + stage (data-as-flag) ----
    if (!isL1) {
      if (step == 0) {
#pragma unroll
        for (int i = 0; i < 4; ++i) {
          int idx = t + i * 256;
          int b = idx >> 7;
          int kc = (idx & 127) << 2;
          *(f32x4*)&hA[b][kc] = *(const f32x4*)(initst + kc);
        }
      } else {
        const unsigned long long* src = h0s + (size_t)(step - 1) * 4096 + wbase;
        unsigned long long v[16];
        unsigned int done = 0;
        while (done != 0xFFFFu) {
#pragma unroll
          for (int j = 0; j < 16; ++j)
            if (!((done >> j) & 1u)) v[j] = ldw(&src[j]);
          unsigned int nd = 0;
#pragma unroll
          for (int j = 0; j < 16; ++j)
            if ((unsigned int)(v[j] >> 32)) nd |= 1u << j;
          done = nd;
          if (done != 0xFFFFu) __builtin_amdgcn_s_sleep(1);
        }
#pragma unroll
        for (int q = 0; q < 4; ++q) {
          f32x4 x;
          x.x = __uint_as_float((unsigned int)v[q * 4 + 0]);
          x.y = __uint_as_float((unsigned int)v[q * 4 + 1]);
          x.z = __uint_as_float((unsigned int)v[q * 4 + 2]);
          x.w = __uint_as_float((unsigned int)v[q * 4 + 3]);
          *(f32x4*)&hA[sb][sk + q * 4] = x;
        }
      }
    } else {
      const unsigned long long* src0 = h0s + (size_t)step * 4096 + wbase;
      const unsigned long long* src1 =
          (step > 0) ? (h1s + (size_t)(step - 1) * 4096 + wbase) : nullptr;
      unsigned long long v0[16], v1[16];
      unsigned int done0 = 0, done1 = src1 ? 0u : 0xFFFFu;
      while ((done0 & done1) != 0xFFFFu) {
#pragma unroll
        for (int j = 0; j < 16; ++j)
          if (!((done0 >> j) & 1u)) v0[j] = ldw(&src0[j]);
        if (src1) {
#pragma unroll
          for (int j = 0; j < 16; ++j)
            if (!((done1 >> j) & 1u)) v1[j] = ldw(&src1[j]);
        }
        unsigned int nd0 = 0, nd1 = done1;
#pragma unroll
        for (int j = 0; j < 16; ++j)
          if ((unsigned int)(v0[j] >> 32)) nd0 |= 1u << j;
        if (src1) {
#pragma unroll
          for (int j = 0; j < 16; ++j)
            if ((unsigned int)(v1[j] >> 32)) nd1 |= 1u << j;
        }
        done0 = nd0; done1 = nd1;
        if ((done0 & done1) != 0xFFFFu) __builtin_amdgcn_s_sleep(1);
      }
#pragma unroll
      for (int q = 0; q < 4; ++q) {
        f32x4 x;
        x.x = __uint_as_float((unsigned int)v0[q * 4 + 0]);
        x.y = __uint_as_float((unsigned int)v0[q * 4 + 1]);
        x.z = __uint_as_float((unsigned int)v0[q * 4 + 2]);
        x.w = __uint_as_float((unsigned int)v0[q * 4 + 3]);
        *(f32x4*)&hA[sb][sk + q * 4] = x;
      }
      if (step == 0) {
#pragma unroll
        for (int i = 0; i < 4; ++i) {
          int idx = t + i * 256;
          int b = idx >> 7;
          int kc = (idx & 127) << 2;
          *(f32x4*)&hB[b][kc] = *(const f32x4*)(initst + 512 + kc);
        }
      } else {
#pragma unroll
        for (int q = 0; q < 4; ++q) {
          f32x4 x;
          x.x = __uint_as_float((unsigned int)v1[q * 4 + 0]);
          x.y = __uint_as_float((unsigned int)v1[q * 4 + 1]);
          x.z = __uint_as_float((unsigned int)v1[q * 4 + 2]);
          x.w = __uint_as_float((unsigned int)v1[q * 4 + 3]);
          *(f32x4*)&hB[sb][sk + q * 4] = x;
        }
      }
    }
    __syncthreads();

    // ---- gate matmul ----
    if (!isL1) {
      float acc0[8], acc1[8];
#pragma unroll
      for (int b = 0; b < 8; ++b) { acc0[b] = 0.f; acc1[b] = 0.f; }
#pragma unroll
      for (int b = 0; b < 8; ++b) {
        const float* hb = &hA[b][0];
#pragma unroll
        for (int j = 0; j < 8; ++j) {
          f32x4 hq = *(const f32x4*)(hb + kg * 4 + j * 64);
          acc0[b] += w[j].x * hq.x + w[j].y * hq.y + w[j].z * hq.z + w[j].w * hq.w;
          acc1[b] += w[8 + j].x * hq.x + w[8 + j].y * hq.y + w[8 + j].z * hq.z + w[8 + j].w * hq.w;
        }
      }
#pragma unroll
      for (int s = 1; s < 16; s <<= 1) {
#pragma unroll
        for (int b = 0; b < 8; ++b) {
          acc0[b] += __shfl_xor(acc0[b], s, 64);
          acc1[b] += __shfl_xor(acc1[b], s, 64);
        }
      }
      if (kg == 0) {
#pragma unroll
        for (int b = 0; b < 8; ++b) {
          gates_s[rg * 2][b] = acc0[b];
          gates_s[rg * 2 + 1][b] = acc1[b];
        }
      }
    } else {
      float acc[8];
#pragma unroll
      for (int b = 0; b < 8; ++b) acc[b] = 0.f;
      const float* hbase = (kg < 8) ? &hA[0][0] : &hB[0][0];
      const int kq = (kg & 7) * 4;
#pragma unroll
      for (int b = 0; b < 8; ++b) {
        const float* hb = hbase + b * H_SZ;
#pragma unroll
        for (int j = 0; j < 16; ++j) {
          f32x4 hq = *(const f32x4*)(hb + kq + j * 32);
          acc[b] += w[j].x * hq.x + w[j].y * hq.y + w[j].z * hq.z + w[j].w * hq.w;
        }
      }
#pragma unroll
      for (int s = 1; s < 16; s <<= 1) {
#pragma unroll
        for (int b = 0; b < 8; ++b) acc[b] += __shfl_xor(acc[b], s, 64);
      }
      if (kg == 0) {
#pragma unroll
        for (int b = 0; b < 8; ++b) gates_s[rg][b] = acc[b];
      }
    }
    __syncthreads();

    // ---- LSTM cell (wave 0) + packed store (data IS the flag) ----
    if (t < nCell) {
      float gi, gf, gg, go;
      if (!isL1) {
        gi = gates_s[cu][cb] + pgi;
        gf = gates_s[8 + cu][cb] + pgf;
        gg = gates_s[16 + cu][cb] + pgg;
        go = gates_s[24 + cu][cb] + pgo;
      } else {
        gi = gates_s[cu][cb] + bgi;
        gf = gates_s[4 + cu][cb] + bgf;
        gg = gates_s[8 + cu][cb] + bgg;
        go = gates_s[12 + cu][cb] + bgo;
      }
      float cn = sigm(gf) * creg + sigm(gi) * tanhf(gg);
      float h = sigm(go) * tanhf(cn);
      creg = cn;
      unsigned long long pk =
          (1ull << 32) | (unsigned long long)(unsigned int)__float_as_uint(h);
      if (!isL1) {
        __hip_atomic_store(&h0s[(size_t)step * 4096 + cb * H_SZ + cunit], pk,
                           __ATOMIC_RELAXED, __HIP_MEMORY_SCOPE_AGENT);
      } else {
        __hip_atomic_store(&h1s[(size_t)step * 4096 + cb * H_SZ + cunit], pk,
                           __ATOMIC_RELAXED, __HIP_MEMORY_SCOPE_AGENT);
        size_t r = (size_t)(cb * S_SZ + step) * H_SZ + cunit;
        unsigned short hh = f2bf(h);
        hs1h[r] = hh;
        hs1l[r] = f2bf(h - bf2f(hh));
      }
    }
    // no end-of-loop barrier: gates_s WAR is covered by next iter's
    // post-stage __syncthreads; hA/hB writes only happen after all threads
    // passed the pre-cell __syncthreads (matmul reads complete).
  }
}

// ---------------------------------------------------------------------------
// VIB head epilogue: std=softplus, mu, sample=mu+sqrt(std)*eps
// ---------------------------------------------------------------------------
__global__ void sample_kernel(const float* __restrict__ stats, const float* __restrict__ eps,
                              unsigned short* __restrict__ sh, unsigned short* __restrict__ sl,
                              float* __restrict__ omu, float* __restrict__ ostd) {
  int gid = blockIdx.x * 256 + threadIdx.x;  // 2097152
  int r = gid >> 9, hh = gid & 511;
  float sp = stats[(size_t)r * 1024 + hh];
  float mu = stats[(size_t)r * 1024 + 512 + hh];
  float sd = (sp > 20.f) ? sp : log1pf(expf(sp));
  float smp = mu + sqrtf(sd) * eps[gid];
  omu[gid] = mu;
  ostd[gid] = sd;
  unsigned short h = f2bf(smp);
  sh[gid] = h;
  sl[gid] = f2bf(smp - bf2f(h));
}

// ---------------------------------------------------------------------------
extern "C" void kernel_launch(void* const* d_in, const int* in_sizes, int n_in,
                              void* d_out, int out_size, void* d_ws, size_t ws_size,
                              hipStream_t stream) {
  const float* emb    = (const float*)d_in[0];
  const float* initst = (const float*)d_in[1];
  const float* w_ih0  = (const float*)d_in[2];
  const float* w_hh0  = (const float*)d_in[3];
  const float* b_ih0  = (const float*)d_in[4];
  const float* b_hh0  = (const float*)d_in[5];
  const float* w_ih1  = (const float*)d_in[6];
  const float* w_hh1  = (const float*)d_in[7];
  const float* b_ih1  = (const float*)d_in[8];
  const float* b_hh1  = (const float*)d_in[9];
  const float* wg     = (const float*)d_in[10];
  const float* bg     = (const float*)d_in[11];
  const float* wd     = (const float*)d_in[12];
  const float* bd     = (const float*)d_in[13];
  const float* eps    = (const float*)d_in[14];
  const int*   x      = (const int*)d_in[15];

  char* ws = (char*)d_ws;
  size_t off = 0;
  auto alloc = [&](size_t sz) {
    void* p = ws + off;
    off = (off + sz + 255) & ~(size_t)255;
    return p;
  };
  unsigned long long* h0s = (unsigned long long*)alloc((size_t)512 * 4096 * 8);
  unsigned long long* h1s = (unsigned long long*)alloc((size_t)512 * 4096 * 8);
  float* b0s             = (float*)alloc(G4H * 4);
  float* b1s             = (float*)alloc(G4H * 4);
  unsigned short* wih0h  = (unsigned short*)alloc((size_t)G4H * E_SZ * 2);
  unsigned short* wih0l  = (unsigned short*)alloc((size_t)G4H * E_SZ * 2);
  unsigned short* wgh    = (unsigned short*)alloc((size_t)1024 * H_SZ * 2);
  unsigned short* wgl    = (unsigned short*)alloc((size_t)1024 * H_SZ * 2);
  unsigned short* wdh    = (unsigned short*)alloc((size_t)V_SZ * H_SZ * 2);
  unsigned short* wdl    = (unsigned short*)alloc((size_t)V_SZ * H_SZ * 2);
  unsigned short* a0h    = (unsigned short*)alloc((size_t)NTOK * E_SZ * 2);
  unsigned short* a0l    = (unsigned short*)alloc((size_t)NTOK * E_SZ * 2);
  float* gx0             = (float*)alloc((size_t)NTOK * G4H * 4);
  unsigned short* smph   = (unsigned short*)alloc((size_t)NTOK * H_SZ * 2);
  unsigned short* smpl   = (unsigned short*)alloc((size_t)NTOK * H_SZ * 2);

  // aliased buffers (lifetimes disjoint):
  //  - hs1 (written by lstm, read by stats GEMM) reuses a0 (dead after gx0 GEMM)
  //  - stats (written after lstm) reuses gx0 (dead after lstm)
  unsigned short* hs1h = a0h;
  unsigned short* hs1l = a0l;
  float* stats         = gx0;

  float* out_logits = (float*)d_out;                       // [4096][32000]
  float* out_mu     = out_logits + (size_t)NTOK * V_SZ;    // [4096][512]
  float* out_std    = out_mu + (size_t)NTOK * H_SZ;

  // clear stamps (graph replays reuse ws)
  (void)hipMemsetAsync(h0s, 0, (size_t)512 * 4096 * 8, stream);
  (void)hipMemsetAsync(h1s, 0, (size_t)512 * 4096 * 8, stream);

  // 1. weight splits
  split_kernel<<<(G4H * E_SZ / 4 + 255) / 256, 256, 0, stream>>>(w_ih0, wih0h, wih0l, G4H * E_SZ / 4);
  split_kernel<<<(1024 * H_SZ / 4 + 255) / 256, 256, 0, stream>>>(wg, wgh, wgl, 1024 * H_SZ / 4);
  split_kernel<<<(V_SZ * H_SZ / 4 + 255) / 256, 256, 0, stream>>>(wd, wdh, wdl, V_SZ * H_SZ / 4);
  bias_sum_kernel<<<8, 256, 0, stream>>>(b_ih0, b_hh0, b_ih1, b_hh1, b0s, b1s);

  // 2. embedding gather + split
  embed_split_kernel<<<NTOK * 128 / 256, 256, 0, stream>>>(emb, x, a0h, a0l);

  // 3. gx0 = emb @ w_ih0^T + b0s
  gemm3_kernel<<<dim3(G4H / 128, NTOK / 128), 256, 0, stream>>>(
      a0h, a0l, wih0h, wih0l, b0s, gx0, NTOK, G4H, E_SZ);

  // 4. sequential LSTM (decoupled persistent blocks, data-as-flag)
  lstm_seq_kernel<<<SEQ_NB, 256, 0, stream>>>(
      gx0, w_hh0, w_ih1, w_hh1, b1s, initst, h0s, h1s, hs1h, hs1l);

  // 5. stats = hs1 @ wg^T + bg
  gemm3_kernel<<<dim3(1024 / 128, NTOK / 128), 256, 0, stream>>>(
      hs1h, hs1l, wgh, wgl, bg, stats, NTOK, 1024, H_SZ);

  // 6. VIB head
  sample_kernel<<<NTOK * H_SZ / 256, 256, 0, stream>>>(stats, eps, smph, smpl, out_mu, out_std);

  // 7. logits = sample @ wd^T + bd
  gemm3_kernel<<<dim3(V_SZ / 128, NTOK / 128), 256, 0, stream>>>(
      smph, smpl, wdh, wdl, bd, out_logits, NTOK, V_SZ, H_SZ);
}

// Round 6
// 3789.460 us; speedup vs baseline: 1.4782x; 1.4782x over previous
//
#include <hip/hip_runtime.h>

// ============================================================================
// SequentialVariationalIB: 2-layer LSTM (B=8,S=512,H=512) + VIB head + decoder
//
//  Sequential core (R6): 64 L0-blocks + 128 L1-blocks, decoupled chains,
//  per-step flag-slot signaling (R4 scheme). h values: producer stores are
//  agent-relaxed atomics (reach the IF coherence point); consumer staging
//  uses PLAIN coalesced vector loads — safe because kernel-launch acquire
//  invalidates all caches and each h line is written before first touch.
//  Gate matmul remapped for 4-row register reuse: LDS read volume per step
//  cut 2x (L0) / 4x (L1); the L1 chain was LDS-pipe-bound.
// ============================================================================

typedef __attribute__((ext_vector_type(4))) float f32x4;
typedef __attribute__((ext_vector_type(8))) short short8;
typedef __attribute__((ext_vector_type(4))) unsigned short u16x4;

#define V_SZ 32000
#define E_SZ 512
#define H_SZ 512
#define B_SZ 8
#define S_SZ 512
#define NTOK 4096            // B*S
#define G4H  2048            // 4*H

// ---------------------------------------------------------------------------
// bf16 helpers (manual RNE)
// ---------------------------------------------------------------------------
__device__ __forceinline__ unsigned short f2bf(float x) {
  unsigned int b = __float_as_uint(x);
  b += 0x7FFFu + ((b >> 16) & 1u);
  return (unsigned short)(b >> 16);
}
__device__ __forceinline__ float bf2f(unsigned short u) {
  return __uint_as_float(((unsigned int)u) << 16);
}

__device__ __forceinline__ void split4(const f32x4 v, u16x4& hv, u16x4& lv) {
  unsigned short h0 = f2bf(v.x); lv.x = f2bf(v.x - bf2f(h0)); hv.x = h0;
  unsigned short h1 = f2bf(v.y); lv.y = f2bf(v.y - bf2f(h1)); hv.y = h1;
  unsigned short h2 = f2bf(v.z); lv.z = f2bf(v.z - bf2f(h2)); hv.z = h2;
  unsigned short h3 = f2bf(v.w); lv.w = f2bf(v.w - bf2f(h3)); hv.w = h3;
}

// ---------------------------------------------------------------------------
// prep kernels
// ---------------------------------------------------------------------------
__global__ void split_kernel(const float* __restrict__ src,
                             unsigned short* __restrict__ hi,
                             unsigned short* __restrict__ lo, int n4) {
  int i = blockIdx.x * 256 + threadIdx.x;
  if (i >= n4) return;
  f32x4 v = ((const f32x4*)src)[i];
  u16x4 hv, lv;
  split4(v, hv, lv);
  ((u16x4*)hi)[i] = hv;
  ((u16x4*)lo)[i] = lv;
}

__global__ void bias_sum_kernel(const float* __restrict__ a0, const float* __restrict__ c0,
                                const float* __restrict__ a1, const float* __restrict__ c1,
                                float* __restrict__ o0, float* __restrict__ o1) {
  int i = blockIdx.x * 256 + threadIdx.x;
  if (i < G4H) { o0[i] = a0[i] + c0[i]; o1[i] = a1[i] + c1[i]; }
}

__global__ void embed_split_kernel(const float* __restrict__ emb, const int* __restrict__ x,
                                   unsigned short* __restrict__ hi, unsigned short* __restrict__ lo) {
  int gid = blockIdx.x * 256 + threadIdx.x;   // NTOK * 128
  int r = gid >> 7;
  int kq = (gid & 127) << 2;
  int tok = x[r];
  f32x4 v = *(const f32x4*)(emb + (size_t)tok * E_SZ + kq);
  u16x4 hv, lv;
  split4(v, hv, lv);
  *(u16x4*)(hi + (size_t)r * E_SZ + kq) = hv;
  *(u16x4*)(lo + (size_t)r * E_SZ + kq) = lv;
}

// ---------------------------------------------------------------------------
// split-bf16 3-product GEMM:  C[M,N] = A[M,K] @ B[N,K]^T + bias
// ---------------------------------------------------------------------------
__device__ __forceinline__ int swz32(int row, int seg) {
  return row * 32 + (((seg ^ (row & 3)) << 3));
}

__global__ __launch_bounds__(256, 2) void gemm3_kernel(
    const unsigned short* __restrict__ Ah, const unsigned short* __restrict__ Al,
    const unsigned short* __restrict__ Bh, const unsigned short* __restrict__ Bl,
    const float* __restrict__ bias, float* __restrict__ C,
    int M, int N, int K) {
  __shared__ unsigned short sAh[128 * 32];
  __shared__ unsigned short sAl[128 * 32];
  __shared__ unsigned short sBh[128 * 32];
  __shared__ unsigned short sBl[128 * 32];

  const int t = threadIdx.x;
  const int lane = t & 63;
  const int wave = t >> 6;
  const int wr = wave >> 1, wc = wave & 1;
  const size_t m0 = (size_t)blockIdx.y * 128;
  const size_t n0 = (size_t)blockIdx.x * 128;

  f32x4 acc[4][4];
#pragma unroll
  for (int i = 0; i < 4; ++i)
#pragma unroll
    for (int j = 0; j < 4; ++j) acc[i][j] = (f32x4){0.f, 0.f, 0.f, 0.f};

  const int r0 = t >> 2;
  const int seg0 = t & 3;

  const int nk = K >> 5;
  for (int ks = 0; ks < nk; ++ks) {
    const int k0 = ks << 5;
    short8 vAh[2], vAl[2], vBh[2], vBl[2];
#pragma unroll
    for (int r = 0; r < 2; ++r) {
      int row = r0 + r * 64;
      size_t ga = (m0 + row) * (size_t)K + k0 + seg0 * 8;
      size_t gb = (n0 + row) * (size_t)K + k0 + seg0 * 8;
      vAh[r] = *(const short8*)(Ah + ga);
      vAl[r] = *(const short8*)(Al + ga);
      vBh[r] = *(const short8*)(Bh + gb);
      vBl[r] = *(const short8*)(Bl + gb);
    }
    __syncthreads();
#pragma unroll
    for (int r = 0; r < 2; ++r) {
      int row = r0 + r * 64;
      int d = swz32(row, seg0);
      *(short8*)(sAh + d) = vAh[r];
      *(short8*)(sAl + d) = vAl[r];
      *(short8*)(sBh + d) = vBh[r];
      *(short8*)(sBl + d) = vBl[r];
    }
    __syncthreads();

    short8 ah[4], al[4], bh[4], bl[4];
    const int seg = lane >> 4;
#pragma unroll
    for (int m = 0; m < 4; ++m) {
      int row = wr * 64 + m * 16 + (lane & 15);
      int d = swz32(row, seg);
      ah[m] = *(const short8*)(sAh + d);
      al[m] = *(const short8*)(sAl + d);
    }
#pragma unroll
    for (int n = 0; n < 4; ++n) {
      int row = wc * 64 + n * 16 + (lane & 15);
      int d = swz32(row, seg);
      bh[n] = *(const short8*)(sBh + d);
      bl[n] = *(const short8*)(sBl + d);
    }
#pragma unroll
    for (int m = 0; m < 4; ++m) {
#pragma unroll
      for (int n = 0; n < 4; ++n) {
        acc[m][n] = __builtin_amdgcn_mfma_f32_16x16x32_bf16(ah[m], bh[n], acc[m][n], 0, 0, 0);
        acc[m][n] = __builtin_amdgcn_mfma_f32_16x16x32_bf16(ah[m], bl[n], acc[m][n], 0, 0, 0);
        acc[m][n] = __builtin_amdgcn_mfma_f32_16x16x32_bf16(al[m], bh[n], acc[m][n], 0, 0, 0);
      }
    }
  }

#pragma unroll
  for (int m = 0; m < 4; ++m) {
#pragma unroll
    for (int n = 0; n < 4; ++n) {
      size_t gr0 = m0 + wr * 64 + m * 16 + ((lane >> 4) << 2);
      size_t gc = n0 + wc * 64 + n * 16 + (lane & 15);
      float bv = bias ? bias[gc] : 0.f;
#pragma unroll
      for (int j = 0; j < 4; ++j) {
        C[(gr0 + j) * (size_t)N + gc] = acc[m][n][j] + bv;
      }
    }
  }
}

// ---------------------------------------------------------------------------
// persistent sequential LSTM kernel — decoupled, fence-free signaling (R4),
// matmul remapped for register row-reuse (R6).
//
// L0 thread map: tb=t>>7 (4 batches), rg=(t>>4)&7 (4 rows), kg=t&15 (32 k).
// L1 thread map: tb=t>>7 (4 batches), rg=(t>>5)&3 (4 rows), kg=t&31
//                (32 k over combined K=1024: hA|hB).
// ---------------------------------------------------------------------------
#define SEQ_NB 192
#define SEQ_NB_L0 64

__device__ __forceinline__ float sigm(float x) { return 1.f / (1.f + expf(-x)); }

__global__ __launch_bounds__(256, 1) void lstm_seq_kernel(
    const float* __restrict__ gx0,    // [4096][2048] (bias folded in)
    const float* __restrict__ w_hh0,  // [2048][512]
    const float* __restrict__ w_ih1,  // [2048][512]
    const float* __restrict__ w_hh1,  // [2048][512]
    const float* __restrict__ b1s,    // [2048]
    const float* __restrict__ initst, // [2][2][512]
    float* __restrict__ h0_all,       // [512][8][512]
    float* __restrict__ h1_all,       // [512][8][512]
    unsigned short* __restrict__ hs1h,// [4096][512]
    unsigned short* __restrict__ hs1l,
    unsigned int* __restrict__ sig0,  // [512][64]
    unsigned int* __restrict__ sig1) {// [512][128]
  const int blk = blockIdx.x;
  const int t = threadIdx.x;
  const bool isL1 = (blk >= SEQ_NB_L0);
  const int lb = isL1 ? (blk - SEQ_NB_L0) : blk;

  __shared__ float hA[8][512];
  __shared__ float hB[8][512];
  __shared__ float gates_s[32][8];

  const int tb = t >> 7;                       // batch group (4 batches)
  const int rg = isL1 ? ((t >> 5) & 3) : ((t >> 4) & 7);
  const int kg = isL1 ? (t & 31) : (t & 15);

  // ---- weights -> registers: 4 rows x 32 k-elems per thread ----
  f32x4 w[4][8];
  if (!isL1) {
#pragma unroll
    for (int rr = 0; rr < 4; ++rr) {
      int rl = rg * 4 + rr;                          // gate-row in [0,32)
      int grow = (rl >> 3) * H_SZ + lb * 8 + (rl & 7);
      const float* src = w_hh0 + (size_t)grow * H_SZ + kg * 4;
#pragma unroll
      for (int j = 0; j < 8; ++j) w[rr][j] = *(const f32x4*)(src + j * 64);
    }
  } else {
#pragma unroll
    for (int rr = 0; rr < 4; ++rr) {
      int rl = rg * 4 + rr;                          // gate-row in [0,16)
      int grow = (rl >> 2) * H_SZ + lb * 4 + (rl & 3);
      const float* s1 = w_ih1 + (size_t)grow * H_SZ + kg * 4;
      const float* s2 = w_hh1 + (size_t)grow * H_SZ + kg * 4;
#pragma unroll
      for (int j = 0; j < 4; ++j) w[rr][j] = *(const f32x4*)(s1 + j * 128);
#pragma unroll
      for (int j = 0; j < 4; ++j) w[rr][4 + j] = *(const f32x4*)(s2 + j * 128);
    }
  }

  // ---- per-lane cell state (wave 0 only) ----
  const int UPB = isL1 ? 4 : 8;
  const int nCell = UPB * 8;                       // 64 (L0) / 32 (L1)
  const int cu = t >> 3, cb = t & 7;
  const int cunit = lb * UPB + cu;
  float creg = 0.f;
  float bgi = 0.f, bgf = 0.f, bgg = 0.f, bgo = 0.f;
  if (t < nCell) {
    creg = initst[1024 + (isL1 ? 512 : 0) + cunit];
    if (isL1) {
      bgi = b1s[cunit];
      bgf = b1s[512 + cunit];
      bgg = b1s[1024 + cunit];
      bgo = b1s[1536 + cunit];
    }
  }

  for (int step = 0; step < 512; ++step) {
    // ---- prefetch gx0 gate rows for this step (cacheable) ----
    float pgi = 0.f, pgf = 0.f, pgg = 0.f, pgo = 0.f;
    if (!isL1 && t < nCell) {
      const float* gx = gx0 + ((size_t)(cb * S_SZ + step)) * G4H + cunit;
      pgi = gx[0];
      pgf = gx[512];
      pgg = gx[1024];
      pgo = gx[1536];
    }

    // ---- wait for inputs (wave 0, relaxed agent loads) ----
    if (t < 64) {
      if (!isL1) {
        if (step > 0) {
          const unsigned int* s0 = sig0 + (size_t)(step - 1) * 64;
          while (true) {
            unsigned int v = __hip_atomic_load(&s0[t], __ATOMIC_RELAXED, __HIP_MEMORY_SCOPE_AGENT);
            if (__all(v != 0)) break;
            __builtin_amdgcn_s_sleep(1);
          }
        }
      } else {
        const unsigned int* s0 = sig0 + (size_t)step * 64;
        const unsigned int* s1 = (step > 0) ? (sig1 + (size_t)(step - 1) * 128) : nullptr;
        while (true) {
          int ok = (__hip_atomic_load(&s0[t], __ATOMIC_RELAXED, __HIP_MEMORY_SCOPE_AGENT) != 0);
          if (s1) {
            ok &= (__hip_atomic_load(&s1[t], __ATOMIC_RELAXED, __HIP_MEMORY_SCOPE_AGENT) != 0);
            ok &= (__hip_atomic_load(&s1[64 + t], __ATOMIC_RELAXED, __HIP_MEMORY_SCOPE_AGENT) != 0);
          }
          if (__all(ok)) break;
          __builtin_amdgcn_s_sleep(1);
        }
      }
    }
    __syncthreads();   // orders staging loads after poll exit

    // ---- stage h into LDS via PLAIN coalesced loads (cold-line coherent) ----
    if (!isL1) {
      const float* src = (step == 0) ? (initst) : (h0_all + (size_t)(step - 1) * 4096);
      if (step == 0) {
#pragma unroll
        for (int i = 0; i < 4; ++i) {
          int idx = t + i * 256;
          int b = idx >> 7;
          int kc = (idx & 127) << 2;
          *(f32x4*)&hA[b][kc] = *(const f32x4*)(initst + kc);
        }
      } else {
#pragma unroll
        for (int i = 0; i < 4; ++i) {
          int idx = t + i * 256;
          int b = idx >> 7;
          int kc = (idx & 127) << 2;
          *(f32x4*)&hA[b][kc] = *(const f32x4*)(src + b * H_SZ + kc);
        }
      }
    } else {
      const float* s0 = h0_all + (size_t)step * 4096;
      const float* s1 = (step == 0) ? nullptr : (h1_all + (size_t)(step - 1) * 4096);
#pragma unroll
      for (int i = 0; i < 4; ++i) {
        int idx = t + i * 256;
        int b = idx >> 7;
        int kc = (idx & 127) << 2;
        *(f32x4*)&hA[b][kc] = *(const f32x4*)(s0 + b * H_SZ + kc);
        f32x4 v1 = s1 ? *(const f32x4*)(s1 + b * H_SZ + kc)
                      : *(const f32x4*)(initst + 512 + kc);
        *(f32x4*)&hB[b][kc] = v1;
      }
    }
    __syncthreads();

    // ---- gate matmul: 4 rows x 4 batches per thread ----
    float acc[4][4];   // [rr][bq]
#pragma unroll
    for (int rr = 0; rr < 4; ++rr)
#pragma unroll
      for (int bq = 0; bq < 4; ++bq) acc[rr][bq] = 0.f;

    if (!isL1) {
#pragma unroll
      for (int bq = 0; bq < 4; ++bq) {
        const float* hb = &hA[tb * 4 + bq][0];
#pragma unroll
        for (int j = 0; j < 8; ++j) {
          f32x4 hq = *(const f32x4*)(hb + kg * 4 + j * 64);
#pragma unroll
          for (int rr = 0; rr < 4; ++rr)
            acc[rr][bq] += w[rr][j].x * hq.x + w[rr][j].y * hq.y +
                           w[rr][j].z * hq.z + w[rr][j].w * hq.w;
        }
      }
      // reduce across 16 kg lanes
#pragma unroll
      for (int s = 1; s < 16; s <<= 1) {
#pragma unroll
        for (int rr = 0; rr < 4; ++rr)
#pragma unroll
          for (int bq = 0; bq < 4; ++bq)
            acc[rr][bq] += __shfl_xor(acc[rr][bq], s, 64);
      }
      if (kg == 0) {
#pragma unroll
        for (int rr = 0; rr < 4; ++rr)
#pragma unroll
          for (int bq = 0; bq < 4; ++bq)
            gates_s[rg * 4 + rr][tb * 4 + bq] = acc[rr][bq];
      }
    } else {
#pragma unroll
      for (int bq = 0; bq < 4; ++bq) {
        const int b = tb * 4 + bq;
        const float* ha = &hA[b][0];
        const float* hbp = &hB[b][0];
#pragma unroll
        for (int j = 0; j < 4; ++j) {
          f32x4 hq = *(const f32x4*)(ha + kg * 4 + j * 128);
#pragma unroll
          for (int rr = 0; rr < 4; ++rr)
            acc[rr][bq] += w[rr][j].x * hq.x + w[rr][j].y * hq.y +
                           w[rr][j].z * hq.z + w[rr][j].w * hq.w;
        }
#pragma unroll
        for (int j = 0; j < 4; ++j) {
          f32x4 hq = *(const f32x4*)(hbp + kg * 4 + j * 128);
#pragma unroll
          for (int rr = 0; rr < 4; ++rr)
            acc[rr][bq] += w[rr][4 + j].x * hq.x + w[rr][4 + j].y * hq.y +
                           w[rr][4 + j].z * hq.z + w[rr][4 + j].w * hq.w;
        }
      }
      // reduce across 32 kg lanes
#pragma unroll
      for (int s = 1; s < 32; s <<= 1) {
#pragma unroll
        for (int rr = 0; rr < 4; ++rr)
#pragma unroll
          for (int bq = 0; bq < 4; ++bq)
            acc[rr][bq] += __shfl_xor(acc[rr][bq], s, 64);
      }
      if (kg == 0) {
#pragma unroll
        for (int rr = 0; rr < 4; ++rr)
#pragma unroll
          for (int bq = 0; bq < 4; ++bq)
            gates_s[rg * 4 + rr][tb * 4 + bq] = acc[rr][bq];
      }
    }
    __syncthreads();

    // ---- LSTM cell (wave 0) + signal ----
    if (t < nCell) {
      float gi, gf, gg, go;
      if (!isL1) {
        gi = gates_s[cu][cb] + pgi;
        gf = gates_s[8 + cu][cb] + pgf;
        gg = gates_s[16 + cu][cb] + pgg;
        go = gates_s[24 + cu][cb] + pgo;
      } else {
        gi = gates_s[cu][cb] + bgi;
        gf = gates_s[4 + cu][cb] + bgf;
        gg = gates_s[8 + cu][cb] + bgg;
        go = gates_s[12 + cu][cb] + bgo;
      }
      float cn = sigm(gf) * creg + sigm(gi) * tanhf(gg);
      float h = sigm(go) * tanhf(cn);
      creg = cn;
      if (!isL1) {
        __hip_atomic_store(&h0_all[(size_t)step * 4096 + cb * H_SZ + cunit], h,
                           __ATOMIC_RELAXED, __HIP_MEMORY_SCOPE_AGENT);
      } else {
        __hip_atomic_store(&h1_all[(size_t)step * 4096 + cb * H_SZ + cunit], h,
                           __ATOMIC_RELAXED, __HIP_MEMORY_SCOPE_AGENT);
        size_t r = (size_t)(cb * S_SZ + step) * H_SZ + cunit;
        unsigned short hh = f2bf(h);
        hs1h[r] = hh;
        hs1l[r] = f2bf(h - bf2f(hh));
      }
    }
    if (t == 0) {
      // producing wave == signaling wave: vmcnt(0) orders the h stores
      // (coherence-point ops) before the flag store; no cache maintenance.
      asm volatile("s_waitcnt vmcnt(0)" ::: "memory");
      unsigned int* slot = isL1 ? (sig1 + (size_t)step * 128 + lb)
                                : (sig0 + (size_t)step * 64 + lb);
      __hip_atomic_store(slot, 1u, __ATOMIC_RELAXED, __HIP_MEMORY_SCOPE_AGENT);
    }
    // no end-of-loop barrier: WAR hazards covered by next iter's post-stage sync
  }
}

// ---------------------------------------------------------------------------
// VIB head epilogue: std=softplus, mu, sample=mu+sqrt(std)*eps
// ---------------------------------------------------------------------------
__global__ void sample_kernel(const float* __restrict__ stats, const float* __restrict__ eps,
                              unsigned short* __restrict__ sh, unsigned short* __restrict__ sl,
                              float* __restrict__ omu, float* __restrict__ ostd) {
  int gid = blockIdx.x * 256 + threadIdx.x;  // 2097152
  int r = gid >> 9, hh = gid & 511;
  float sp = stats[(size_t)r * 1024 + hh];
  float mu = stats[(size_t)r * 1024 + 512 + hh];
  float sd = (sp > 20.f) ? sp : log1pf(expf(sp));
  float smp = mu + sqrtf(sd) * eps[gid];
  omu[gid] = mu;
  ostd[gid] = sd;
  unsigned short h = f2bf(smp);
  sh[gid] = h;
  sl[gid] = f2bf(smp - bf2f(h));
}

// ---------------------------------------------------------------------------
extern "C" void kernel_launch(void* const* d_in, const int* in_sizes, int n_in,
                              void* d_out, int out_size, void* d_ws, size_t ws_size,
                              hipStream_t stream) {
  const float* emb    = (const float*)d_in[0];
  const float* initst = (const float*)d_in[1];
  const float* w_ih0  = (const float*)d_in[2];
  const float* w_hh0  = (const float*)d_in[3];
  const float* b_ih0  = (const float*)d_in[4];
  const float* b_hh0  = (const float*)d_in[5];
  const float* w_ih1  = (const float*)d_in[6];
  const float* w_hh1  = (const float*)d_in[7];
  const float* b_ih1  = (const float*)d_in[8];
  const float* b_hh1  = (const float*)d_in[9];
  const float* wg     = (const float*)d_in[10];
  const float* bg     = (const float*)d_in[11];
  const float* wd     = (const float*)d_in[12];
  const float* bd     = (const float*)d_in[13];
  const float* eps    = (const float*)d_in[14];
  const int*   x      = (const int*)d_in[15];

  char* ws = (char*)d_ws;
  size_t off = 0;
  auto alloc = [&](size_t sz) {
    void* p = ws + off;
    off = (off + sz + 255) & ~(size_t)255;
    return p;
  };
  unsigned int* sig0     = (unsigned int*)alloc((size_t)512 * 64 * 4);
  unsigned int* sig1     = (unsigned int*)alloc((size_t)512 * 128 * 4);
  float* b0s             = (float*)alloc(G4H * 4);
  float* b1s             = (float*)alloc(G4H * 4);
  unsigned short* wih0h  = (unsigned short*)alloc((size_t)G4H * E_SZ * 2);
  unsigned short* wih0l  = (unsigned short*)alloc((size_t)G4H * E_SZ * 2);
  unsigned short* wgh    = (unsigned short*)alloc((size_t)1024 * H_SZ * 2);
  unsigned short* wgl    = (unsigned short*)alloc((size_t)1024 * H_SZ * 2);
  unsigned short* wdh    = (unsigned short*)alloc((size_t)V_SZ * H_SZ * 2);
  unsigned short* wdl    = (unsigned short*)alloc((size_t)V_SZ * H_SZ * 2);
  unsigned short* a0h    = (unsigned short*)alloc((size_t)NTOK * E_SZ * 2);
  unsigned short* a0l    = (unsigned short*)alloc((size_t)NTOK * E_SZ * 2);
  float* gx0             = (float*)alloc((size_t)NTOK * G4H * 4);
  float* h0_all          = (float*)alloc((size_t)512 * 4096 * 4);
  float* h1_all          = (float*)alloc((size_t)512 * 4096 * 4);
  unsigned short* hs1h   = (unsigned short*)alloc((size_t)NTOK * H_SZ * 2);
  unsigned short* hs1l   = (unsigned short*)alloc((size_t)NTOK * H_SZ * 2);
  float* stats           = (float*)alloc((size_t)NTOK * 1024 * 4);
  unsigned short* smph   = (unsigned short*)alloc((size_t)NTOK * H_SZ * 2);
  unsigned short* smpl   = (unsigned short*)alloc((size_t)NTOK * H_SZ * 2);

  float* out_logits = (float*)d_out;                       // [4096][32000]
  float* out_mu     = out_logits + (size_t)NTOK * V_SZ;    // [4096][512]
  float* out_std    = out_mu + (size_t)NTOK * H_SZ;

  // reset flag slots (graph replays reuse ws)
  (void)hipMemsetAsync(sig0, 0, (size_t)512 * 64 * 4, stream);
  (void)hipMemsetAsync(sig1, 0, (size_t)512 * 128 * 4, stream);

  // 1. weight splits
  split_kernel<<<(G4H * E_SZ / 4 + 255) / 256, 256, 0, stream>>>(w_ih0, wih0h, wih0l, G4H * E_SZ / 4);
  split_kernel<<<(1024 * H_SZ / 4 + 255) / 256, 256, 0, stream>>>(wg, wgh, wgl, 1024 * H_SZ / 4);
  split_kernel<<<(V_SZ * H_SZ / 4 + 255) / 256, 256, 0, stream>>>(wd, wdh, wdl, V_SZ * H_SZ / 4);
  bias_sum_kernel<<<8, 256, 0, stream>>>(b_ih0, b_hh0, b_ih1, b_hh1, b0s, b1s);

  // 2. embedding gather + split
  embed_split_kernel<<<NTOK * 128 / 256, 256, 0, stream>>>(emb, x, a0h, a0l);

  // 3. gx0 = emb @ w_ih0^T + b0s
  gemm3_kernel<<<dim3(G4H / 128, NTOK / 128), 256, 0, stream>>>(
      a0h, a0l, wih0h, wih0l, b0s, gx0, NTOK, G4H, E_SZ);

  // 4. sequential LSTM (decoupled persistent blocks)
  lstm_seq_kernel<<<SEQ_NB, 256, 0, stream>>>(
      gx0, w_hh0, w_ih1, w_hh1, b1s, initst, h0_all, h1_all, hs1h, hs1l, sig0, sig1);

  // 5. stats = hs1 @ wg^T + bg
  gemm3_kernel<<<dim3(1024 / 128, NTOK / 128), 256, 0, stream>>>(
      hs1h, hs1l, wgh, wgl, bg, stats, NTOK, 1024, H_SZ);

  // 6. VIB head
  sample_kernel<<<NTOK * H_SZ / 256, 256, 0, stream>>>(stats, eps, smph, smpl, out_mu, out_std);

  // 7. logits = sample @ wd^T + bd
  gemm3_kernel<<<dim3(V_SZ / 128, NTOK / 128), 256, 0, stream>>>(
      smph, smpl, wdh, wdl, bd, out_logits, NTOK, V_SZ, H_SZ);
}